// Round 3
// baseline (116.939 us; speedup 1.0000x reference)
//
#include <hip/hip_runtime.h>
#include <math.h>

// ContrastiveLoss — x (8,128,16,8,8) fp32.
// feats[n,f] = x[b*131072 + f*1024 + r], n=(b<<10)|r, N=8192, F=128.
// loss = 10 + ln( sum_{i!=j} exp(10*dot(x̂_i,x̂_j) - 10) )   (unit rows => s<=10)
//
// Round 3: full-GPU normalize (256 blocks, LDS-staged, all phases <=2-way bank
// aliasing = free), triangular gram launch (2080 blocks), finale fused into
// gram via device-scope atomics (64 slots + counter; last block does the log).
//
// Swizzled X̂ layout (unchanged, round-2-verified): row-group rg=n>>4 (16 rows,
// 2048 shorts). 16B chunk (t*64 + q*16 + (n&15)) holds k = t*32+q*8+j, j=0..7
// — exactly the mfma_f32_16x16x32_bf16 A/B fragment order for lane q*16+(n&15).
//
// ws: acc double[64] @0; counter uint @512; Xs bf16[8192*128] @32768 (2MB).

#define NBLK 2080  // 64*65/2 upper-triangle tiles
#define NSLOT 64

typedef __attribute__((ext_vector_type(8))) short short8;
typedef __bf16 bf16_t;
typedef __attribute__((ext_vector_type(8))) bf16_t bf16x8;
typedef __attribute__((ext_vector_type(4))) float f32x4;

#if __has_builtin(__builtin_amdgcn_exp2f)
#define EXP2F(x) __builtin_amdgcn_exp2f(x)
#else
#define EXP2F(x) exp2f(x)
#endif

// Adapter: compiles whether the mfma builtin takes short8 or bf16x8 operands.
struct Frag {
    short8 s;
    __device__ operator short8() const { return s; }
    __device__ operator bf16x8() const { return __builtin_bit_cast(bf16x8, s); }
};

__device__ inline short f2bf(float f) {  // RNE fp32->bf16 (inputs finite)
    unsigned u = __float_as_uint(f);
    u += 0x7fff + ((u >> 16) & 1);
    return (short)(u >> 16);
}

// ---------------------------------------------------------------------------
// Kernel 1: normalize + swizzle, full GPU. Block = 32 rows (same b).
// Phase 1: coalesced global read (each element once) -> LDS (pad 33, 2-way max).
// Phase 2: 512 output chunks/block, 2/thread, consecutive tid -> consecutive
// 16B chunks (coalesced); LDS reads 2-way aliased (free).
// Also zeroes the atomic slots + counter for kernel 2.
// ---------------------------------------------------------------------------
__global__ __launch_bounds__(256)
void normalize_kernel(const float* __restrict__ x, short* __restrict__ Xs,
                      double* __restrict__ acc, unsigned* __restrict__ counter) {
    if (blockIdx.x == 0) {
        if (threadIdx.x < NSLOT) acc[threadIdx.x] = 0.0;
        if (threadIdx.x == NSLOT) *counter = 0u;
    }
    __shared__ float ldsf[128][33];
    __shared__ float ssred[8][32];
    __shared__ float invs[32];
    const int tid = threadIdx.x;
    const int b  = blockIdx.x >> 5;
    const int r0 = (blockIdx.x & 31) * 32;
    const int rl = tid & 31, fp = tid >> 5;   // row-in-block, feature-part
    const float* px = x + b * 131072 + r0 + rl;
    float ss = 0.f;
#pragma unroll
    for (int j = 0; j < 16; ++j) {
        int f = fp * 16 + j;
        float v = px[f * 1024];
        ldsf[f][rl] = v;
        ss = fmaf(v, v, ss);
    }
    ssred[fp][rl] = ss;
    __syncthreads();
    if (tid < 32) {
        float s = 0.f;
#pragma unroll
        for (int k = 0; k < 8; ++k) s += ssred[k][tid];
        invs[tid] = 1.0f / fmaxf(sqrtf(s), 1e-12f);
    }
    __syncthreads();
#pragma unroll
    for (int p = 0; p < 2; ++p) {
        int c = p * 256 + tid;                       // chunk id, output-ordered
        int grp = c >> 8, tt = (c >> 6) & 3, q = (c >> 4) & 3, r16 = c & 15;
        int lr = grp * 16 + r16;                     // local row 0..31
        float inv = invs[lr];
        union { short s[8]; int4 v; } u;
#pragma unroll
        for (int j = 0; j < 8; ++j)
            u.s[j] = f2bf(ldsf[tt * 32 + q * 8 + j][lr] * inv);
        int rg = (((b << 10) + r0) >> 4) + grp;      // global row-group
        *(int4*)(Xs + ((rg * 256 + tt * 64 + q * 16 + r16) << 3)) = u.v;
    }
}

// ---------------------------------------------------------------------------
// Kernel 2: 128x128 Gram tile via mfma_f32_16x16x32_bf16 + fused exp-sum +
// fused final reduction (atomic slots; last block computes the log).
// Triangular grid: 2080 blocks, J>=I only. LDS 64KB -> 2 blocks/CU.
// ---------------------------------------------------------------------------
__global__ __launch_bounds__(256)
void gram_lse_kernel(const short* __restrict__ Xs, double* __restrict__ acc,
                     unsigned* __restrict__ counter, float* __restrict__ out) {
    const int bid = blockIdx.x;
    // decode upper-triangle (row I has 64-I entries) — scalar, <=64 iters
    int I = 0, off = 0;
    while (off + (64 - I) <= bid) { off += 64 - I; ++I; }
    const int J = I + (bid - off);
    const int tid = threadIdx.x;

    __shared__ short lds[32768];  // A [0,16384) shorts, B [16384,32768)
    {
        const int4* srcA = (const int4*)(Xs + I * 16384);  // 8 row-groups, linear
        const int4* srcB = (const int4*)(Xs + J * 16384);
        int4* dst = (int4*)lds;
#pragma unroll
        for (int q = 0; q < 8; ++q) {
            dst[q * 256 + tid]        = srcA[q * 256 + tid];
            dst[2048 + q * 256 + tid] = srcB[q * 256 + tid];
        }
    }
    __syncthreads();

    const int lane = tid & 63;
    const int w    = tid >> 6;
    const int gi0  = (w & 1) * 4;   // row-group base within tile
    const int gj0  = (w >> 1) * 4;

    f32x4 a_acc[4][4];
#pragma unroll
    for (int i = 0; i < 4; ++i)
#pragma unroll
        for (int j = 0; j < 4; ++j) a_acc[i][j] = (f32x4){0.f, 0.f, 0.f, 0.f};

    const short8* ldsA = (const short8*)lds;
    const short8* ldsB = (const short8*)(lds + 16384);
#pragma unroll
    for (int t = 0; t < 4; ++t) {                    // K-steps of 32
        short8 a[4], b[4];
#pragma unroll
        for (int i = 0; i < 4; ++i) a[i] = ldsA[(gi0 + i) * 256 + t * 64 + lane];
#pragma unroll
        for (int j = 0; j < 4; ++j) b[j] = ldsB[(gj0 + j) * 256 + t * 64 + lane];
#pragma unroll
        for (int i = 0; i < 4; ++i)
#pragma unroll
            for (int j = 0; j < 4; ++j)
                a_acc[i][j] = __builtin_amdgcn_mfma_f32_16x16x32_bf16(
                    Frag{a[i]}, Frag{b[j]}, a_acc[i][j], 0, 0, 0);
    }

    // Epilogue: C/D layout col=lane&15, row=(lane>>4)*4+reg (verified m89/m91).
    // exp(10d-10) = exp2(C*d - C), C = 10*log2(e)
    const float C = 14.426950408889634f;
    const bool diagT = (I == J);
    const int quad = lane >> 4, colL = lane & 15;
    float lsum = 0.f;
#pragma unroll
    for (int i = 0; i < 4; ++i) {
        const int rbase = (gi0 + i) * 16 + quad * 4;   // row within tile
#pragma unroll
        for (int j = 0; j < 4; ++j) {
            const int cbase = (gj0 + j) * 16 + colL;   // col within tile
#pragma unroll
            for (int g = 0; g < 4; ++g) {
                if (diagT && (rbase + g == cbase)) continue;
                lsum += EXP2F(fmaf(C, a_acc[i][j][g], -C));
            }
        }
    }
    double dsum = diagT ? (double)lsum : 2.0 * (double)lsum;
#pragma unroll
    for (int o = 32; o > 0; o >>= 1) dsum += __shfl_down(dsum, o, 64);
    __shared__ double red[4];
    __shared__ int lastflag;
    if (lane == 0) red[w] = dsum;
    __syncthreads();
    if (tid == 0) {
        double bsum = red[0] + red[1] + red[2] + red[3];
        // all cross-block traffic via device-scope atomics (XCD-coherent)
        __hip_atomic_fetch_add(&acc[bid & (NSLOT - 1)], bsum,
                               __ATOMIC_RELEASE, __HIP_MEMORY_SCOPE_AGENT);
        unsigned old = __hip_atomic_fetch_add(counter, 1u,
                               __ATOMIC_ACQ_REL, __HIP_MEMORY_SCOPE_AGENT);
        lastflag = (old == NBLK - 1) ? 1 : 0;
    }
    __syncthreads();
    if (lastflag && tid < NSLOT) {
        double s = __hip_atomic_load(&acc[tid], __ATOMIC_ACQUIRE,
                                     __HIP_MEMORY_SCOPE_AGENT);
#pragma unroll
        for (int o = 32; o > 0; o >>= 1) s += __shfl_down(s, o, 64);
        if (tid == 0) out[0] = (float)(10.0 + log(s));
    }
}

extern "C" void kernel_launch(void* const* d_in, const int* in_sizes, int n_in,
                              void* d_out, int out_size, void* d_ws, size_t ws_size,
                              hipStream_t stream) {
    const float* x = (const float*)d_in[0];
    float* out = (float*)d_out;
    double* acc = (double*)d_ws;                        // 64 doubles
    unsigned* counter = (unsigned*)((char*)d_ws + 512); // 1 uint
    short* Xs = (short*)((char*)d_ws + 32768);          // 2MB swizzled bf16 X̂

    normalize_kernel<<<256, 256, 0, stream>>>(x, Xs, acc, counter);
    gram_lse_kernel<<<NBLK, 256, 0, stream>>>(Xs, acc, counter, out);
}

// Round 4
// 86.157 us; speedup vs baseline: 1.3573x; 1.3573x over previous
//
#include <hip/hip_runtime.h>
#include <math.h>

// ContrastiveLoss — x (8,128,16,8,8) fp32.
// feats[n,f] = x[b*131072 + f*1024 + r], n=(b<<10)|r, N=8192, F=128.
// loss = 10 + ln( sum_{i!=j} exp(10*dot(x̂_i,x̂_j) - 10) )   (unit rows => s<=10)
//
// Round 4: gram reads MFMA fragments DIRECTLY from global/L2 (the swizzled
// layout makes every fragment a lane-linear dwordx4) — no LDS, no barriers,
// no atomics. Per-wave partials; tiny final reduce kernel.
//
// Swizzled X̂ layout (round-2-verified): row-group rg=n>>4 (16 rows, 2048
// shorts). 16B chunk (t*64 + q*16 + (n&15)) holds k = t*32+q*8+j, j=0..7 —
// exactly the mfma_f32_16x16x32_bf16 A/B fragment order for lane q*16+(n&15).
//
// ws: partials double[8320] @0 (66.6KB); Xs bf16[8192*128] @131072 (2MB).

#define NBLK 2080   // 64*65/2 upper-triangle 128x128 tiles

typedef __attribute__((ext_vector_type(8))) short short8;
typedef __bf16 bf16_t;
typedef __attribute__((ext_vector_type(8))) bf16_t bf16x8;
typedef __attribute__((ext_vector_type(4))) float f32x4;

// Adapter: compiles whether the mfma builtin takes short8 or bf16x8 operands.
struct Frag {
    short8 s;
    __device__ operator short8() const { return s; }
    __device__ operator bf16x8() const { return __builtin_bit_cast(bf16x8, s); }
};

__device__ inline short f2bf(float f) {  // RNE fp32->bf16 (inputs finite)
    unsigned u = __float_as_uint(f);
    u += 0x7fff + ((u >> 16) & 1);
    return (short)(u >> 16);
}

// ---------------------------------------------------------------------------
// Kernel 1: normalize + swizzle, full GPU. Block = 32 rows (same b).
// Phase 1: coalesced global read (each element once) -> LDS (pad 33).
// Phase 2: 512 output chunks/block, consecutive tid -> consecutive 16B chunks.
// All LDS phases <=2-way bank aliasing (free on CDNA4).
// ---------------------------------------------------------------------------
__global__ __launch_bounds__(256)
void normalize_kernel(const float* __restrict__ x, short* __restrict__ Xs) {
    __shared__ float ldsf[128][33];
    __shared__ float ssred[8][32];
    __shared__ float invs[32];
    const int tid = threadIdx.x;
    const int b  = blockIdx.x >> 5;
    const int r0 = (blockIdx.x & 31) * 32;
    const int rl = tid & 31, fp = tid >> 5;   // row-in-block, feature-part
    const float* px = x + b * 131072 + r0 + rl;
    float ss = 0.f;
#pragma unroll
    for (int j = 0; j < 16; ++j) {
        int f = fp * 16 + j;
        float v = px[f * 1024];
        ldsf[f][rl] = v;
        ss = fmaf(v, v, ss);
    }
    ssred[fp][rl] = ss;
    __syncthreads();
    if (tid < 32) {
        float s = 0.f;
#pragma unroll
        for (int k = 0; k < 8; ++k) s += ssred[k][tid];
        invs[tid] = 1.0f / fmaxf(sqrtf(s), 1e-12f);
    }
    __syncthreads();
#pragma unroll
    for (int p = 0; p < 2; ++p) {
        int c = p * 256 + tid;                       // chunk id, output-ordered
        int grp = c >> 8, tt = (c >> 6) & 3, q = (c >> 4) & 3, r16 = c & 15;
        int lr = grp * 16 + r16;                     // local row 0..31
        float inv = invs[lr];
        union { short s[8]; int4 v; } u;
#pragma unroll
        for (int j = 0; j < 8; ++j)
            u.s[j] = f2bf(ldsf[tt * 32 + q * 8 + j][lr] * inv);
        int rg = (((b << 10) + r0) >> 4) + grp;      // global row-group
        *(int4*)(Xs + ((rg * 256 + tt * 64 + q * 16 + r16) << 3)) = u.v;
    }
}

// ---------------------------------------------------------------------------
// Kernel 2: 128x128 Gram tile, fragments loaded straight from global (L2).
// No LDS, no barriers. 4 waves/block, each wave a 64x64 region, K=128 in 4
// double-buffered steps of 32. Per-wave partial written to its own slot.
// ---------------------------------------------------------------------------
__global__ __launch_bounds__(256)
void gram_lse_kernel(const short* __restrict__ Xs, double* __restrict__ partials) {
    const int bid = blockIdx.x;
    int I = 0, off = 0;                  // upper-triangle decode, <=64 scalar iters
    while (off + (64 - I) <= bid) { off += 64 - I; ++I; }
    const int J = I + (bid - off);
    const int tid = threadIdx.x;
    const int lane = tid & 63, w = tid >> 6;
    const int gi0 = (w & 1) * 4;         // A row-group base within tile
    const int gj0 = (w >> 1) * 4;        // B row-group base within tile

    // fragment chunk (g*256 + t*64 + lane) within the tile's 2048 chunks
    const short8* A = (const short8*)(Xs + I * 16384) + gi0 * 256 + lane;
    const short8* B = (const short8*)(Xs + J * 16384) + gj0 * 256 + lane;

    f32x4 acc[4][4];
#pragma unroll
    for (int i = 0; i < 4; ++i)
#pragma unroll
        for (int j = 0; j < 4; ++j) acc[i][j] = (f32x4){0.f, 0.f, 0.f, 0.f};

    short8 a[2][4], b[2][4];
#pragma unroll
    for (int i = 0; i < 4; ++i) { a[0][i] = A[i * 256]; b[0][i] = B[i * 256]; }
#pragma unroll
    for (int t = 0; t < 4; ++t) {        // fully unrolled; compiler renames bufs
        const int cur = t & 1, nxt = cur ^ 1;
        if (t < 3) {
#pragma unroll
            for (int i = 0; i < 4; ++i) {
                a[nxt][i] = A[i * 256 + (t + 1) * 64];
                b[nxt][i] = B[i * 256 + (t + 1) * 64];
            }
        }
#pragma unroll
        for (int i = 0; i < 4; ++i)
#pragma unroll
            for (int j = 0; j < 4; ++j)
                acc[i][j] = __builtin_amdgcn_mfma_f32_16x16x32_bf16(
                    Frag{a[cur][i]}, Frag{b[cur][j]}, acc[i][j], 0, 0, 0);
    }

    // Epilogue: C/D layout col=lane&15, row=(lane>>4)*4+reg (verified m89/m91).
    // exp(10d-10) = exp2(C*d - C), C = 10*log2(e)
    const float C = 14.426950408889634f;
    const bool diagT = (I == J);
    const int quad = lane >> 4, colL = lane & 15;
    float lsum = 0.f;
#pragma unroll
    for (int i = 0; i < 4; ++i) {
        const int rbase = (gi0 + i) * 16 + quad * 4;   // row within tile
#pragma unroll
        for (int j = 0; j < 4; ++j) {
            const int cbase = (gj0 + j) * 16 + colL;   // col within tile
#pragma unroll
            for (int g = 0; g < 4; ++g) {
                if (diagT && (rbase + g == cbase)) continue;
                lsum += exp2f(fmaf(C, acc[i][j][g], -C));
            }
        }
    }
    double dsum = diagT ? (double)lsum : 2.0 * (double)lsum;
#pragma unroll
    for (int o = 32; o > 0; o >>= 1) dsum += __shfl_down(dsum, o, 64);
    if (lane == 0) partials[bid * 4 + w] = dsum;   // per-wave slot, no barrier
}

// ---------------------------------------------------------------------------
// Kernel 3: out = 10 + ln(sum of 8320 per-wave partials)
// ---------------------------------------------------------------------------
__global__ __launch_bounds__(256)
void final_kernel(const double* __restrict__ partials, float* __restrict__ out) {
    double s = 0.0;
    for (int i = threadIdx.x; i < NBLK * 4; i += 256) s += partials[i];
#pragma unroll
    for (int o = 32; o > 0; o >>= 1) s += __shfl_down(s, o, 64);
    __shared__ double red[4];
    if ((threadIdx.x & 63) == 0) red[threadIdx.x >> 6] = s;
    __syncthreads();
    if (threadIdx.x == 0)
        out[0] = (float)(10.0 + log(red[0] + red[1] + red[2] + red[3]));
}

extern "C" void kernel_launch(void* const* d_in, const int* in_sizes, int n_in,
                              void* d_out, int out_size, void* d_ws, size_t ws_size,
                              hipStream_t stream) {
    const float* x = (const float*)d_in[0];
    float* out = (float*)d_out;
    double* partials = (double*)d_ws;                 // 8320 doubles
    short* Xs = (short*)((char*)d_ws + 131072);       // 2MB swizzled bf16 X̂

    normalize_kernel<<<256, 256, 0, stream>>>(x, Xs);
    gram_lse_kernel<<<NBLK, 256, 0, stream>>>(Xs, partials);
    final_kernel<<<1, 256, 0, stream>>>(partials, out);
}